// Round 2
// baseline (1196.126 us; speedup 1.0000x reference)
//
#include <hip/hip_runtime.h>
#include <hip/hip_bf16.h>
#include <math.h>

// BitNet MLP: out = BitLinear2(gelu(BitLinear1(x)))
// All GEMMs reformulated as exact int8 GEMMs (quantized acts x ternary weights),
// scales folded into a single f32 alpha per GEMM.

#define TOKENS 8192
#define DMODEL 2048
#define DFF    8192
#define NW     16777216   // 8192*2048 == elements of x, W1, W2

using i32x4 = __attribute__((ext_vector_type(4))) int;

#define GLD16_TO_LDS(g, l) __builtin_amdgcn_global_load_lds( \
    (const __attribute__((address_space(1))) void*)(g), \
    (__attribute__((address_space(3))) void*)(l), 16, 0, 0)

// ---------------- reductions: sum(|v|) and max(|v|) ----------------
__global__ void reduce_abs_kernel(const float* __restrict__ in, int n,
                                  float* __restrict__ sum_out,
                                  unsigned int* __restrict__ max_out) {
    int idx = blockIdx.x * blockDim.x + threadIdx.x;
    int stride = gridDim.x * blockDim.x;
    const float4* in4 = (const float4*)in;
    int n4 = n >> 2;
    float s = 0.f, m = 0.f;
    for (int i = idx; i < n4; i += stride) {
        float4 v = in4[i];
        float ax = fabsf(v.x), ay = fabsf(v.y), az = fabsf(v.z), aw = fabsf(v.w);
        s += ax + ay + az + aw;
        m = fmaxf(m, fmaxf(fmaxf(ax, ay), fmaxf(az, aw)));
    }
    #pragma unroll
    for (int off = 32; off; off >>= 1) {
        s += __shfl_xor(s, off);
        m = fmaxf(m, __shfl_xor(m, off));
    }
    __shared__ float ss[4], sm[4];
    int wave = threadIdx.x >> 6, lane = threadIdx.x & 63;
    if (lane == 0) { ss[wave] = s; sm[wave] = m; }
    __syncthreads();
    if (threadIdx.x == 0) {
        float ts = ss[0] + ss[1] + ss[2] + ss[3];
        float tm = fmaxf(fmaxf(sm[0], sm[1]), fmaxf(sm[2], sm[3]));
        atomicAdd(sum_out, ts);
        atomicMax(max_out, __float_as_uint(tm));
    }
}

// ---------------- activation quantize: q = rint(clamp(v*127/max, +-127)) ----------------
__global__ void quant_act_kernel(const float* __restrict__ in,
                                 signed char* __restrict__ out, int n,
                                 const unsigned int* __restrict__ maxp) {
    float scale = 127.0f / __uint_as_float(*maxp);
    int idx = blockIdx.x * blockDim.x + threadIdx.x;
    int stride = gridDim.x * blockDim.x;
    const float4* in4 = (const float4*)in;
    unsigned int* out4 = (unsigned int*)out;
    int n4 = n >> 2;
    for (int i = idx; i < n4; i += stride) {
        float4 v = in4[i];
        int q0 = (int)rintf(fminf(fmaxf(v.x * scale, -127.f), 127.f));
        int q1 = (int)rintf(fminf(fmaxf(v.y * scale, -127.f), 127.f));
        int q2 = (int)rintf(fminf(fmaxf(v.z * scale, -127.f), 127.f));
        int q3 = (int)rintf(fminf(fmaxf(v.w * scale, -127.f), 127.f));
        out4[i] = (q0 & 0xff) | ((q1 & 0xff) << 8) | ((q2 & 0xff) << 16) | ((q3 & 0xff) << 24);
    }
}

// ---------------- ternary weight quantize: t = rint(clamp(w/mean|w|, +-1)) ----------------
__global__ void quant_w_kernel(const float* __restrict__ in,
                               signed char* __restrict__ out, int n,
                               const float* __restrict__ sump) {
    float s = *sump / 16777216.0f;   // mean(|W|), both W are 8192x2048
    int idx = blockIdx.x * blockDim.x + threadIdx.x;
    int stride = gridDim.x * blockDim.x;
    const float4* in4 = (const float4*)in;
    unsigned int* out4 = (unsigned int*)out;
    int n4 = n >> 2;
    for (int i = idx; i < n4; i += stride) {
        float4 v = in4[i];
        int q0 = (int)rintf(fminf(fmaxf(v.x / s, -1.f), 1.f));
        int q1 = (int)rintf(fminf(fmaxf(v.y / s, -1.f), 1.f));
        int q2 = (int)rintf(fminf(fmaxf(v.z / s, -1.f), 1.f));
        int q3 = (int)rintf(fminf(fmaxf(v.w / s, -1.f), 1.f));
        out4[i] = (q0 & 0xff) | ((q1 & 0xff) << 8) | ((q2 & 0xff) << 16) | ((q3 & 0xff) << 24);
    }
}

// ---------------- int8 NT GEMM, 128x128 tile, BK=64 bytes (m97 structure) --------------
// C[M,N] = A[M,K] * B[N,K]^T  (both row-major, K contiguous)
// EPI 0: h = gelu(dot*alpha1 + b1), write f32, atomicMax |h|
// EPI 1: out = dot*alpha2 + b2, write f32
// EPI 2: like 0 but no store (max-only pass, small-ws path)
// EPI 3: like 0 but store int8 quantized with known max (small-ws path)
template <int EPI>
__global__ __launch_bounds__(256) void gemm_i8(
    const signed char* __restrict__ A, const signed char* __restrict__ B,
    void* __restrict__ Cv, const float* __restrict__ bias,
    int K, int N, const float* __restrict__ sc,
    unsigned int* __restrict__ max_out)
{
    __shared__ __align__(16) unsigned char sA[128 * 64];
    __shared__ __align__(16) unsigned char sB[128 * 64];
    __shared__ float smax[4];

    const int tid = threadIdx.x;
    const int lane = tid & 63;
    const int wave = tid >> 6;
    const int wm = wave >> 1;        // wave row (0..1), wave tile 64x64
    const int wn = wave & 1;         // wave col (0..1)
    const long rowBase = (long)blockIdx.y * 128;
    const long colBase = (long)blockIdx.x * 128;
    const signed char* Ab = A + rowBase * (long)K;
    const signed char* Bb = B + colBase * (long)K;

    i32x4 acc[4][4] = {};

    const int o0 = tid * 16;   // staging: 8192B tile, 256 thr x 16B x 2 iters

    for (int kk = 0; kk < K; kk += 64) {
        #pragma unroll
        for (int it = 0; it < 2; ++it) {
            int o = it * 4096 + o0;
            int r = o >> 6, cb = o & 63;
            GLD16_TO_LDS(Ab + (long)r * K + kk + cb, &sA[o]);
            GLD16_TO_LDS(Bb + (long)r * K + kk + cb, &sB[o]);
        }
        __syncthreads();

        i32x4 a[4], b[4];
        #pragma unroll
        for (int m = 0; m < 4; ++m) {
            int off = (wm * 64 + m * 16 + (lane & 15)) * 64 + (lane >> 4) * 16;
            a[m] = *(const i32x4*)(&sA[off]);
        }
        #pragma unroll
        for (int n = 0; n < 4; ++n) {
            int off = (wn * 64 + n * 16 + (lane & 15)) * 64 + (lane >> 4) * 16;
            b[n] = *(const i32x4*)(&sB[off]);
        }
        #pragma unroll
        for (int m = 0; m < 4; ++m)
            #pragma unroll
            for (int n = 0; n < 4; ++n)
                acc[m][n] = __builtin_amdgcn_mfma_i32_16x16x64_i8(a[m], b[n], acc[m][n], 0, 0, 0);
        __syncthreads();
    }

    // ---- epilogue ----
    float wmax = 0.f;
    if (EPI == 0 || EPI == 2 || EPI == 3) {
        float scale_w = sc[0] / 16777216.0f;                        // mean|W1|
        float maxx = __uint_as_float(((const unsigned int*)sc)[3]); // max|x|
        float alpha = scale_w * maxx / 127.0f;
        float qscale = 0.f;
        if (EPI == 3)
            qscale = 127.0f / __uint_as_float(((const unsigned int*)sc)[6]);
        #pragma unroll
        for (int m = 0; m < 4; ++m) {
            int row_l = wm * 64 + m * 16 + ((lane >> 4) * 4);
            #pragma unroll
            for (int n = 0; n < 4; ++n) {
                int col = (int)colBase + wn * 64 + n * 16 + (lane & 15);
                float bv = bias[col];
                #pragma unroll
                for (int r = 0; r < 4; ++r) {
                    long grow = rowBase + row_l + r;
                    float v = (float)acc[m][n][r] * alpha + bv;
                    float g = 0.5f * v * (1.0f + erff(v * 0.70710678118654752f));
                    if (EPI == 0) ((float*)Cv)[grow * N + col] = g;
                    if (EPI == 3) {
                        float q = rintf(fminf(fmaxf(g * qscale, -127.f), 127.f));
                        ((signed char*)Cv)[grow * N + col] = (signed char)(int)q;
                    }
                    wmax = fmaxf(wmax, fabsf(g));
                }
            }
        }
    } else { // EPI == 1
        float scale_w = sc[1] / 16777216.0f;                        // mean|W2|
        float maxg = __uint_as_float(((const unsigned int*)sc)[6]); // max|gelu(h)|
        float alpha = scale_w * maxg / 127.0f;
        #pragma unroll
        for (int m = 0; m < 4; ++m) {
            int row_l = wm * 64 + m * 16 + ((lane >> 4) * 4);
            #pragma unroll
            for (int n = 0; n < 4; ++n) {
                int col = (int)colBase + wn * 64 + n * 16 + (lane & 15);
                float bv = bias[col];
                #pragma unroll
                for (int r = 0; r < 4; ++r) {
                    long grow = rowBase + row_l + r;
                    ((float*)Cv)[grow * N + col] = (float)acc[m][n][r] * alpha + bv;
                }
            }
        }
    }

    if (EPI == 0 || EPI == 2) {
        #pragma unroll
        for (int off = 32; off; off >>= 1)
            wmax = fmaxf(wmax, __shfl_xor(wmax, off));
        if (lane == 0) smax[wave] = wmax;
        __syncthreads();
        if (tid == 0) {
            float bm = fmaxf(fmaxf(smax[0], smax[1]), fmaxf(smax[2], smax[3]));
            atomicMax(max_out, __float_as_uint(bm));
        }
    }
}

extern "C" void kernel_launch(void* const* d_in, const int* in_sizes, int n_in,
                              void* d_out, int out_size, void* d_ws, size_t ws_size,
                              hipStream_t stream) {
    const float* x  = (const float*)d_in[0];
    const float* W1 = (const float*)d_in[1];
    const float* b1 = (const float*)d_in[2];
    const float* W2 = (const float*)d_in[3];
    const float* b2 = (const float*)d_in[4];
    float* out = (float*)d_out;

    char* ws = (char*)d_ws;
    // scalar slots (floats): [0]=sum|W1| [1]=sum|W2| [2]=sum|x|(dummy) [3]=max|x|(u32)
    //                        [4],[5]=dummy maxes    [6]=max|gelu|(u32)
    float* sc = (float*)ws;
    signed char* xq  = (signed char*)(ws + 256);
    signed char* w1q = xq + (size_t)NW;
    signed char* w2q = w1q + (size_t)NW;
    signed char* hq  = w2q + (size_t)NW;                       // 64 MB
    float* h = (float*)(hq + (size_t)TOKENS * DFF);            // 256 MB (big-ws path)
    size_t needA = 256 + 3ULL * NW + (size_t)TOKENS * DFF * 5ULL;
    bool bigws = ws_size >= needA;

    hipMemsetAsync(sc, 0, 64, stream);

    reduce_abs_kernel<<<1024, 256, 0, stream>>>(x,  NW, &sc[2], (unsigned int*)&sc[3]);
    reduce_abs_kernel<<<1024, 256, 0, stream>>>(W1, NW, &sc[0], (unsigned int*)&sc[4]);
    reduce_abs_kernel<<<1024, 256, 0, stream>>>(W2, NW, &sc[1], (unsigned int*)&sc[5]);

    quant_act_kernel<<<1024, 256, 0, stream>>>(x, xq, NW, (const unsigned int*)&sc[3]);
    quant_w_kernel<<<1024, 256, 0, stream>>>(W1, w1q, NW, &sc[0]);
    quant_w_kernel<<<1024, 256, 0, stream>>>(W2, w2q, NW, &sc[1]);

    dim3 g1(DFF / 128, TOKENS / 128);     // (64, 64)
    if (bigws) {
        gemm_i8<0><<<g1, 256, 0, stream>>>(xq, w1q, (void*)h, b1, DMODEL, DFF, sc,
                                           (unsigned int*)&sc[6]);
        quant_act_kernel<<<4096, 256, 0, stream>>>(h, hq, TOKENS * DFF,
                                                   (const unsigned int*)&sc[6]);
    } else {
        // small workspace: pass 1 computes max|gelu| only, pass 2 recomputes + quantizes
        gemm_i8<2><<<g1, 256, 0, stream>>>(xq, w1q, nullptr, b1, DMODEL, DFF, sc,
                                           (unsigned int*)&sc[6]);
        gemm_i8<3><<<g1, 256, 0, stream>>>(xq, w1q, (void*)hq, b1, DMODEL, DFF, sc,
                                           (unsigned int*)&sc[6]);
    }

    dim3 g2(DMODEL / 128, TOKENS / 128);  // (16, 64)
    gemm_i8<1><<<g2, 256, 0, stream>>>(hq, w2q, (void*)out, b2, DFF, DMODEL, sc, nullptr);
}

// Round 4
// 997.866 us; speedup vs baseline: 1.1987x; 1.1987x over previous
//
#include <hip/hip_runtime.h>
#include <hip/hip_bf16.h>
#include <math.h>

// BitNet MLP: out = BitLinear2(gelu(BitLinear1(x)))
// Exact int8 GEMMs (quantized acts x ternary weights), scales folded into f32 alpha.
// GEMM: 256x256 tile, 8 waves, BK=64B, double-buffered LDS with counted-vmcnt
// prefetch (never vmcnt(0) in main loop), fragment-major LDS layout (conflict-free).

#define TOKENS 8192
#define DMODEL 2048
#define DFF    8192
#define NW     16777216   // 8192*2048 == elements of x, W1, W2

using i32x4 = __attribute__((ext_vector_type(4))) int;

#define GLD16_TO_LDS(g, l) __builtin_amdgcn_global_load_lds( \
    (const __attribute__((address_space(1))) void*)(g), \
    (__attribute__((address_space(3))) void*)(l), 16, 0, 0)

// ---------------- reductions: sum(|v|) and max(|v|) (UNCHANGED: absmax stability) ----
__global__ void reduce_abs_kernel(const float* __restrict__ in, int n,
                                  float* __restrict__ sum_out,
                                  unsigned int* __restrict__ max_out) {
    int idx = blockIdx.x * blockDim.x + threadIdx.x;
    int stride = gridDim.x * blockDim.x;
    const float4* in4 = (const float4*)in;
    int n4 = n >> 2;
    float s = 0.f, m = 0.f;
    for (int i = idx; i < n4; i += stride) {
        float4 v = in4[i];
        float ax = fabsf(v.x), ay = fabsf(v.y), az = fabsf(v.z), aw = fabsf(v.w);
        s += ax + ay + az + aw;
        m = fmaxf(m, fmaxf(fmaxf(ax, ay), fmaxf(az, aw)));
    }
    #pragma unroll
    for (int off = 32; off; off >>= 1) {
        s += __shfl_xor(s, off);
        m = fmaxf(m, __shfl_xor(m, off));
    }
    __shared__ float ss[4], sm[4];
    int wave = threadIdx.x >> 6, lane = threadIdx.x & 63;
    if (lane == 0) { ss[wave] = s; sm[wave] = m; }
    __syncthreads();
    if (threadIdx.x == 0) {
        float ts = ss[0] + ss[1] + ss[2] + ss[3];
        float tm = fmaxf(fmaxf(sm[0], sm[1]), fmaxf(sm[2], sm[3]));
        atomicAdd(sum_out, ts);
        atomicMax(max_out, __float_as_uint(tm));
    }
}

// ---------------- activation quantize (UNCHANGED) ----------------
__global__ void quant_act_kernel(const float* __restrict__ in,
                                 signed char* __restrict__ out, int n,
                                 const unsigned int* __restrict__ maxp) {
    float scale = 127.0f / __uint_as_float(*maxp);
    int idx = blockIdx.x * blockDim.x + threadIdx.x;
    int stride = gridDim.x * blockDim.x;
    const float4* in4 = (const float4*)in;
    unsigned int* out4 = (unsigned int*)out;
    int n4 = n >> 2;
    for (int i = idx; i < n4; i += stride) {
        float4 v = in4[i];
        int q0 = (int)rintf(fminf(fmaxf(v.x * scale, -127.f), 127.f));
        int q1 = (int)rintf(fminf(fmaxf(v.y * scale, -127.f), 127.f));
        int q2 = (int)rintf(fminf(fmaxf(v.z * scale, -127.f), 127.f));
        int q3 = (int)rintf(fminf(fmaxf(v.w * scale, -127.f), 127.f));
        out4[i] = (q0 & 0xff) | ((q1 & 0xff) << 8) | ((q2 & 0xff) << 16) | ((q3 & 0xff) << 24);
    }
}

// ---------------- ternary weight quantize (UNCHANGED) ----------------
__global__ void quant_w_kernel(const float* __restrict__ in,
                               signed char* __restrict__ out, int n,
                               const float* __restrict__ sump) {
    float s = *sump / 16777216.0f;
    int idx = blockIdx.x * blockDim.x + threadIdx.x;
    int stride = gridDim.x * blockDim.x;
    const float4* in4 = (const float4*)in;
    unsigned int* out4 = (unsigned int*)out;
    int n4 = n >> 2;
    for (int i = idx; i < n4; i += stride) {
        float4 v = in4[i];
        int q0 = (int)rintf(fminf(fmaxf(v.x / s, -1.f), 1.f));
        int q1 = (int)rintf(fminf(fmaxf(v.y / s, -1.f), 1.f));
        int q2 = (int)rintf(fminf(fmaxf(v.z / s, -1.f), 1.f));
        int q3 = (int)rintf(fminf(fmaxf(v.w / s, -1.f), 1.f));
        out4[i] = (q0 & 0xff) | ((q1 & 0xff) << 8) | ((q2 & 0xff) << 16) | ((q3 & 0xff) << 24);
    }
}

// A&S 7.1.26 erf (abs err <= 1.5e-7) -> exact-erf GELU, ~14 VALU ops vs erff's ~28
__device__ __forceinline__ float gelu_exact(float v) {
    float x  = v * 0.70710678118654752f;
    float ax = fabsf(x);
    float t  = __builtin_amdgcn_rcpf(__builtin_fmaf(0.3275911f, ax, 1.0f));
    float p  = __builtin_fmaf(1.061405429f, t, -1.453152027f);
    p = __builtin_fmaf(p, t, 1.421413741f);
    p = __builtin_fmaf(p, t, -0.284496736f);
    p = __builtin_fmaf(p, t, 0.254829592f);
    p = p * t;
    float e = __expf(-ax * ax);
    float erfabs = __builtin_fmaf(-p, e, 1.0f);
    float er = copysignf(erfabs, x);
    return 0.5f * v * (1.0f + er);
}

// ---------------- int8 NT GEMM, 256x256 tile, 8 waves, counted-vmcnt pipeline -------
// C[M,N] = A[M,K] * B[N,K]^T. LDS layout is fragment-major: 16B chunk of
// (row, kc) stored at off = (row>>4)*1024 + kc*256 + (row&15)*16, so each MFMA
// fragment read is a linear  base + lane*16  ds_read_b128 sweep (conflict-free),
// and global_load_lds dest (tid*16, linear) satisfies the wave-uniform rule.
// EPI 0: h = gelu(dot*alpha1 + b1) f32 store + atomicMax |h|
// EPI 1: out = dot*alpha2 + b2 f32 store
// EPI 2: gelu max only (small-ws)    EPI 3: gelu -> int8 store with known max
template <int EPI>
__global__ __launch_bounds__(512, 2) void gemm_i8_v2(
    const signed char* __restrict__ A, const signed char* __restrict__ B,
    void* __restrict__ Cv, const float* __restrict__ bias,
    int K, int N, int nbx_lg2, const float* __restrict__ sc,
    unsigned int* __restrict__ max_out)
{
    __shared__ __align__(16) unsigned char sA[2][16384];
    __shared__ __align__(16) unsigned char sB[2][16384];
    __shared__ float smax[8];

    const int tid  = threadIdx.x;
    const int lane = tid & 63;
    const int wave = tid >> 6;
    const int wr   = wave >> 2;   // 0..1  (row half of 256)
    const int wn   = wave & 3;    // 0..3  (col quarter of 256)

    // XCD-aware bijective swizzle (gridDim.x % 8 == 0 for both GEMMs)
    const int cpx = gridDim.x >> 3;
    const int bid = blockIdx.x;
    const int nid = (bid & 7) * cpx + (bid >> 3);
    const int bx  = nid & ((1 << nbx_lg2) - 1);
    const int by  = nid >> nbx_lg2;

    const long rowBase = (long)by * 256;
    const long colBase = (long)bx * 256;
    const signed char* Ab = A + rowBase * (long)K;
    const signed char* Bb = B + colBase * (long)K;
    const int NT = K >> 6;        // K-tiles of 64 bytes (>= 2 always here)

    i32x4 acc[8][4] = {};

    // stage K-tile t into buffer bf: 4 global_load_lds x16B per thread (A0,B0,A1,B1)
    auto stage = [&](int t, int bf) {
        const long kk = (long)t << 6;
        #pragma unroll
        for (int it = 0; it < 2; ++it) {
            int off = it * 8192 + tid * 16;        // 0..16383, linear dest
            int fr  = off >> 10;
            int kc  = (off >> 8) & 3;
            int r   = (off >> 4) & 15;
            long row = (long)(fr * 16 + r);
            long src = row * K + kk + kc * 16;
            GLD16_TO_LDS(Ab + src, &sA[bf][off]);
            GLD16_TO_LDS(Bb + src, &sB[bf][off]);
        }
    };

    // prologue: tiles 0 and 1 in flight; wait only tile 0 (4 loads outstanding)
    stage(0, 0);
    stage(1, 1);
    asm volatile("s_waitcnt vmcnt(4)" ::: "memory");
    __builtin_amdgcn_s_barrier();

    for (int t = 0; t < NT; ++t) {
        const int c = t & 1;
        i32x4 bfr[4];
        #pragma unroll
        for (int n = 0; n < 4; ++n)
            bfr[n] = *(const i32x4*)&sB[c][(wn * 4 + n) * 1024 + lane * 16];
        #pragma unroll
        for (int m = 0; m < 8; ++m) {
            i32x4 afr = *(const i32x4*)&sA[c][(wr * 8 + m) * 1024 + lane * 16];
            #pragma unroll
            for (int n = 0; n < 4; ++n)
                acc[m][n] = __builtin_amdgcn_mfma_i32_16x16x64_i8(afr, bfr[n], acc[m][n], 0, 0, 0);
        }
        // all this wave's LDS reads are retired (consumed by MFMA), then barrier:
        // after it, every wave is done reading buf c -> safe to overwrite.
        asm volatile("s_waitcnt lgkmcnt(0)" ::: "memory");
        __builtin_amdgcn_s_barrier();
        if (t + 2 < NT) {
            stage(t + 2, c);                       // 4 more loads in flight
            asm volatile("s_waitcnt vmcnt(4)" ::: "memory");   // tile t+1 landed
        } else {
            asm volatile("s_waitcnt vmcnt(0)" ::: "memory");   // drain tail
        }
        __builtin_amdgcn_s_barrier();              // t+1 visible to all waves
    }

    // ---- epilogue ----
    float wmax = 0.f;
    if (EPI == 0 || EPI == 2 || EPI == 3) {
        float scale_w = sc[0] / 16777216.0f;                        // mean|W1|
        float maxx = __uint_as_float(((const unsigned int*)sc)[3]); // max|x|
        float alpha = scale_w * maxx / 127.0f;
        float qscale = 0.f;
        if (EPI == 3)
            qscale = 127.0f / __uint_as_float(((const unsigned int*)sc)[6]);
        #pragma unroll
        for (int m = 0; m < 8; ++m) {
            int row_l = wr * 128 + m * 16 + ((lane >> 4) * 4);
            #pragma unroll
            for (int n = 0; n < 4; ++n) {
                int col = (int)colBase + wn * 64 + n * 16 + (lane & 15);
                float bv = bias[col];
                #pragma unroll
                for (int r = 0; r < 4; ++r) {
                    long grow = rowBase + row_l + r;
                    float v = (float)acc[m][n][r] * alpha + bv;
                    float g = gelu_exact(v);
                    if (EPI == 0) ((float*)Cv)[grow * N + col] = g;
                    if (EPI == 3) {
                        float q = rintf(fminf(fmaxf(g * qscale, -127.f), 127.f));
                        ((signed char*)Cv)[grow * N + col] = (signed char)(int)q;
                    }
                    wmax = fmaxf(wmax, fabsf(g));
                }
            }
        }
    } else { // EPI == 1
        float scale_w = sc[1] / 16777216.0f;                        // mean|W2|
        float maxg = __uint_as_float(((const unsigned int*)sc)[6]); // max|gelu|
        float alpha = scale_w * maxg / 127.0f;
        #pragma unroll
        for (int m = 0; m < 8; ++m) {
            int row_l = wr * 128 + m * 16 + ((lane >> 4) * 4);
            #pragma unroll
            for (int n = 0; n < 4; ++n) {
                int col = (int)colBase + wn * 64 + n * 16 + (lane & 15);
                float bv = bias[col];
                #pragma unroll
                for (int r = 0; r < 4; ++r) {
                    long grow = rowBase + row_l + r;
                    ((float*)Cv)[grow * N + col] = (float)acc[m][n][r] * alpha + bv;
                }
            }
        }
    }

    if (EPI == 0 || EPI == 2) {
        #pragma unroll
        for (int off = 32; off; off >>= 1)
            wmax = fmaxf(wmax, __shfl_xor(wmax, off));
        if (lane == 0) smax[wave] = wmax;
        __syncthreads();
        if (tid == 0) {
            float bm = smax[0];
            #pragma unroll
            for (int w = 1; w < 8; ++w) bm = fmaxf(bm, smax[w]);
            atomicMax(max_out, __float_as_uint(bm));
        }
    }
}

extern "C" void kernel_launch(void* const* d_in, const int* in_sizes, int n_in,
                              void* d_out, int out_size, void* d_ws, size_t ws_size,
                              hipStream_t stream) {
    const float* x  = (const float*)d_in[0];
    const float* W1 = (const float*)d_in[1];
    const float* b1 = (const float*)d_in[2];
    const float* W2 = (const float*)d_in[3];
    const float* b2 = (const float*)d_in[4];
    float* out = (float*)d_out;

    char* ws = (char*)d_ws;
    // scalar slots (floats): [0]=sum|W1| [1]=sum|W2| [2]=sum|x|(dummy) [3]=max|x|(u32)
    //                        [4],[5]=dummy maxes    [6]=max|gelu|(u32)
    float* sc = (float*)ws;
    signed char* xq  = (signed char*)(ws + 256);
    signed char* w1q = xq + (size_t)NW;
    signed char* w2q = w1q + (size_t)NW;
    signed char* hq  = w2q + (size_t)NW;                       // 64 MB
    float* h = (float*)(hq + (size_t)TOKENS * DFF);            // 256 MB (big-ws path)
    size_t needA = 256 + 3ULL * NW + (size_t)TOKENS * DFF * 5ULL;
    bool bigws = ws_size >= needA;

    hipMemsetAsync(sc, 0, 64, stream);

    reduce_abs_kernel<<<1024, 256, 0, stream>>>(x,  NW, &sc[2], (unsigned int*)&sc[3]);
    reduce_abs_kernel<<<1024, 256, 0, stream>>>(W1, NW, &sc[0], (unsigned int*)&sc[4]);
    reduce_abs_kernel<<<1024, 256, 0, stream>>>(W2, NW, &sc[1], (unsigned int*)&sc[5]);

    quant_act_kernel<<<1024, 256, 0, stream>>>(x, xq, NW, (const unsigned int*)&sc[3]);
    quant_w_kernel<<<1024, 256, 0, stream>>>(W1, w1q, NW, &sc[0]);
    quant_w_kernel<<<1024, 256, 0, stream>>>(W2, w2q, NW, &sc[1]);

    // GEMM1: M=8192 N=8192 K=2048 -> 32x32 = 1024 blocks, NBX=32 (lg 5)
    if (bigws) {
        gemm_i8_v2<0><<<1024, 512, 0, stream>>>(xq, w1q, (void*)h, b1, DMODEL, DFF, 5,
                                                sc, (unsigned int*)&sc[6]);
        quant_act_kernel<<<4096, 256, 0, stream>>>(h, hq, TOKENS * DFF,
                                                   (const unsigned int*)&sc[6]);
    } else {
        gemm_i8_v2<2><<<1024, 512, 0, stream>>>(xq, w1q, nullptr, b1, DMODEL, DFF, 5,
                                                sc, (unsigned int*)&sc[6]);
        gemm_i8_v2<3><<<1024, 512, 0, stream>>>(xq, w1q, (void*)hq, b1, DMODEL, DFF, 5,
                                                sc, (unsigned int*)&sc[6]);
    }

    // GEMM2: M=8192 N=2048 K=8192 -> 32x8 = 256 blocks, NBX=8 (lg 3)
    gemm_i8_v2<1><<<256, 512, 0, stream>>>(hq, w2q, (void*)out, b2, DFF, DMODEL, 3,
                                           sc, nullptr);
}